// Round 17
// baseline (206.629 us; speedup 1.0000x reference)
//
#include <hip/hip_runtime.h>
#include <hip/hip_bf16.h>
#include <float.h>

#define B_ 1024
#define H_ 512
#define N_ (B_ * 64)
#define FFN_ 2048
#define OUT_ 86

typedef __bf16 bf16_t;
typedef __attribute__((ext_vector_type(8))) __bf16 bf16x8;
typedef __attribute__((ext_vector_type(4))) float f32x4;

__device__ __forceinline__ float wred_sum(float v) {
#pragma unroll
  for (int m = 32; m; m >>= 1) v += __shfl_xor(v, m);
  return v;
}
__device__ __forceinline__ float wred_max(float v) {
#pragma unroll
  for (int m = 32; m; m >>= 1) v = fmaxf(v, __shfl_xor(v, m));
  return v;
}

__device__ __forceinline__ void gload_lds16(const void* g, void* l) {
  __builtin_amdgcn_global_load_lds((const __attribute__((address_space(1))) unsigned int*)g,
                                   (__attribute__((address_space(3))) unsigned int*)l, 16, 0, 0);
}

// f32 tiled GEMM, 64x64 tile, BK=16, 4x4 accum. A split across two row blocks.
template <bool BT, bool BIAS>
__global__ __launch_bounds__(256) void gemm64(const float* __restrict__ A1, const float* __restrict__ A2,
                                              int M1, const float* __restrict__ Bm,
                                              const float* __restrict__ bias, float* __restrict__ C,
                                              int N, int K) {
  __shared__ float As[16][68];
  __shared__ float Bs[16][68];
  const int bm = blockIdx.x * 64, bn = blockIdx.y * 64;
  const float* __restrict__ A = (bm < M1) ? (A1 + (size_t)bm * K) : (A2 + (size_t)(bm - M1) * K);
  const int t = threadIdx.x;
  const int tx = t & 15, ty = t >> 4;
  float acc[4][4] = {};
  for (int k0 = 0; k0 < K; k0 += 16) {
#pragma unroll
    for (int i = 0; i < 4; i++) {
      int m = (t >> 4) + i * 16;
      As[t & 15][m] = A[(size_t)m * K + k0 + (t & 15)];
    }
    if (BT) {
#pragma unroll
      for (int i = 0; i < 4; i++) {
        int n = (t >> 4) + i * 16;
        Bs[t & 15][n] = Bm[(size_t)(bn + n) * K + k0 + (t & 15)];
      }
    } else {
#pragma unroll
      for (int i = 0; i < 4; i++) {
        int kk = (t >> 6) + i * 4;
        Bs[kk][t & 63] = Bm[(size_t)(k0 + kk) * N + bn + (t & 63)];
      }
    }
    __syncthreads();
#pragma unroll
    for (int kk = 0; kk < 16; kk++) {
      float4 av = *(const float4*)&As[kk][ty * 4];
      float4 bv = *(const float4*)&Bs[kk][tx * 4];
      float a_[4] = {av.x, av.y, av.z, av.w};
      float b_[4] = {bv.x, bv.y, bv.z, bv.w};
#pragma unroll
      for (int i = 0; i < 4; i++)
#pragma unroll
        for (int j = 0; j < 4; j++) acc[i][j] += a_[i] * b_[j];
    }
    __syncthreads();
  }
#pragma unroll
  for (int i = 0; i < 4; i++) {
    int m = bm + ty * 4 + i;
    float tmp[4];
#pragma unroll
    for (int j = 0; j < 4; j++) {
      float x = acc[i][j];
      if (BIAS) x += bias[bn + tx * 4 + j];
      tmp[j] = x;
    }
    float4 v;
    v.x = tmp[0]; v.y = tmp[1]; v.z = tmp[2]; v.w = tmp[3];
    *(float4*)&C[(size_t)m * N + bn + tx * 4] = v;
  }
}

// Fused scores+softmax+pool: CONTINUOUS-ISSUE ring pipeline.
// r16 post-mortem: burst-32-loads-then-wait keeps HBM at ~1/3 duty (phase-locked
// load/compute). Here each wave keeps 8 loads outstanding at EVERY instant of
// pass A via a 4-row asm-pinned ring + counted vmcnt(6); consume is pure FMA.
// sched_barrier(0) fences both sides of the consume (rule #18 + forces true
// ring-slot reuse so liveness stays ~90 regs). Batch wred + block softmax after.
// Pass B: L2-warm plain re-read for the pool. launch_bounds(256,4): 16 waves/CU,
// pass A has NO barriers -> wave phases drift, HBM stays fed.
__global__ __launch_bounds__(256, 4) void k_atoms10(const float* __restrict__ atomL, const float* __restrict__ atomR,
                                                    const float* __restrict__ uLR,
                                                    float* __restrict__ scoresL, float* __restrict__ scoresR,
                                                    float* __restrict__ pL, float* __restrict__ pR) {
  const int pair = blockIdx.x;                 // 0..2047
  const int side = pair >> 10, b = pair & 1023;
  const int t = threadIdx.x, wave = t >> 6, lane = t & 63;

  __shared__ float s_all[64];
  __shared__ float s_nrm[64];
  __shared__ float pp[4][512];

  const float* __restrict__ atom = side ? atomR : atomL;
  const float* __restrict__ u = uLR + (size_t)pair * H_;
  f32x4 u0 = *(const f32x4*)&u[lane * 4];
  f32x4 u1 = *(const f32x4*)&u[256 + lane * 4];

  const float* __restrict__ base = atom + ((size_t)b * 64 + wave * 16) * H_ + lane * 4;

  // ---- pass A: ring-pipelined dots (8 loads always in flight) ----
  f32x4 R0[4], R1[4];
#pragma unroll
  for (int r = 0; r < 4; r++) {
    const float* rp = base + (size_t)r * H_;
    asm volatile("global_load_dwordx4 %0, %1, off" : "=&v"(R0[r]) : "v"(rp) : "memory");
    asm volatile("global_load_dwordx4 %0, %1, off" : "=&v"(R1[r]) : "v"(rp + 256) : "memory");
  }

  float d[16];
#pragma unroll
  for (int i = 0; i < 16; i++) {
    if (i <= 12)      asm volatile("s_waitcnt vmcnt(6)" ::: "memory");
    else if (i == 13) asm volatile("s_waitcnt vmcnt(4)" ::: "memory");
    else if (i == 14) asm volatile("s_waitcnt vmcnt(2)" ::: "memory");
    else              asm volatile("s_waitcnt vmcnt(0)" ::: "memory");
    __builtin_amdgcn_sched_barrier(0);   // rule #18: consumers stay after the wait
    const int s = i & 3;                 // compile-time ring index (rule #20)
    d[i] = R0[s].x * u0.x + R0[s].y * u0.y + R0[s].z * u0.z + R0[s].w * u0.w +
           R1[s].x * u1.x + R1[s].y * u1.y + R1[s].z * u1.z + R1[s].w * u1.w;
    __builtin_amdgcn_sched_barrier(0);   // consume complete BEFORE slot re-issue
    if (i + 4 < 16) {
      const float* rp = base + (size_t)(i + 4) * H_;
      asm volatile("global_load_dwordx4 %0, %1, off" : "=&v"(R0[s]) : "v"(rp) : "memory");
      asm volatile("global_load_dwordx4 %0, %1, off" : "=&v"(R1[s]) : "v"(rp + 256) : "memory");
    }
  }

  // ---- batch reduction + block softmax ----
#pragma unroll
  for (int i = 0; i < 16; i++) d[i] = wred_sum(d[i]);
  if (lane < 16) {
    float myv = 0.f;
#pragma unroll
    for (int i = 0; i < 16; i++) myv = (lane == i) ? d[i] : myv;  // static idx
    s_all[wave * 16 + lane] = myv;
  }
  __syncthreads();
  {
    float sv = s_all[lane];
    float M = wred_max(sv);
    float e = __expf(sv - M);
    float Z = wred_sum(e);
    float w_n = e / Z;
    if (wave == 0) {
      s_nrm[lane] = w_n;
      (side ? scoresR : scoresL)[(size_t)b * 64 + lane] = w_n;
    }
  }
  __syncthreads();

  // ---- pass B: weighted pool, L2-warm plain re-read ----
  f32x4 q0 = {0.f, 0.f, 0.f, 0.f}, q1 = {0.f, 0.f, 0.f, 0.f};
#pragma unroll
  for (int i = 0; i < 16; i++) {
    const float w = s_nrm[wave * 16 + i];
    f32x4 x0 = *(const f32x4*)(base + (size_t)i * H_);
    f32x4 x1 = *(const f32x4*)(base + (size_t)i * H_ + 256);
    q0.x += w * x0.x; q0.y += w * x0.y; q0.z += w * x0.z; q0.w += w * x0.w;
    q1.x += w * x1.x; q1.y += w * x1.y; q1.z += w * x1.z; q1.w += w * x1.w;
  }
  *(f32x4*)&pp[wave][lane * 4] = q0;
  *(f32x4*)&pp[wave][256 + lane * 4] = q1;
  __syncthreads();

  float v0 = pp[0][t] + pp[1][t] + pp[2][t] + pp[3][t];
  float v1 = pp[0][t + 256] + pp[1][t + 256] + pp[2][t + 256] + pp[3][t + 256];
  float* p = (side ? pR : pL) + (size_t)b * H_;
  p[t] = v0;
  p[t + 256] = v1;
}

// perturbation + bf16 pair assembly
__global__ __launch_bounds__(512) void k_pert(const float* __restrict__ lo, const float* __restrict__ ro,
                                              const float* __restrict__ noise,
                                              const float* __restrict__ pL, const float* __restrict__ pR,
                                              float* __restrict__ h_out, float* __restrict__ h_pert,
                                              bf16_t* __restrict__ pairbf) {
  const int b = blockIdx.x, t = threadIdx.x;
  float nv = noise[(size_t)b * H_ + t];
  float sq = nv * nv;
  sq = wred_sum(sq);
  __shared__ float red[8];
  if ((t & 63) == 0) red[t >> 6] = sq;
  __syncthreads();
  float tot = 0.f;
#pragma unroll
  for (int i = 0; i < 8; i++) tot += red[i];
  float nrm = fmaxf(sqrtf(tot), 1e-12f);
  float nn = nv / nrm * 0.1f;
  float h = ro[(size_t)b * H_ + t] * pL[(size_t)b * H_ + t];
  float tt = lo[(size_t)b * H_ + t] * pR[(size_t)b * H_ + t];
  float sh = (h > 0.f) ? 1.f : ((h < 0.f) ? -1.f : 0.f);
  float st = (tt > 0.f) ? 1.f : ((tt < 0.f) ? -1.f : 0.f);
  float hp = h + sh * nn;
  float tp = tt + st * nn;
  h_out[(size_t)b * H_ + t] = h;
  h_pert[(size_t)b * H_ + t] = hp;
  pairbf[(size_t)b * 1024 + t] = (bf16_t)hp;
  pairbf[(size_t)b * 1024 + 512 + t] = (bf16_t)tp;
}

// W1 [1024][2048] f32 -> W1t [2048][1024] bf16 (transpose + cast, LDS tiled)
__global__ __launch_bounds__(256) void k_w1t(const float* __restrict__ W1, bf16_t* __restrict__ W1t) {
  __shared__ float tile[32][33];
  const int bx = blockIdx.x;
  const int by = blockIdx.y;
  const int tx = threadIdx.x & 31, ty = threadIdx.x >> 5;
#pragma unroll
  for (int i = ty; i < 32; i += 8)
    tile[i][tx] = W1[(size_t)(by * 32 + i) * FFN_ + bx * 32 + tx];
  __syncthreads();
#pragma unroll
  for (int i = ty; i < 32; i += 8)
    W1t[(size_t)(bx * 32 + i) * 1024 + by * 32 + tx] = (bf16_t)tile[tx][i];
}

// FFN1 via MFMA bf16 (64x64 tile, XOR-swizzled source + matching swizzled read)
__global__ __launch_bounds__(256) void k_ffn1(const bf16_t* __restrict__ Abf, const bf16_t* __restrict__ Bt,
                                              const float* __restrict__ bias, float* __restrict__ C) {
  __shared__ bf16_t As[64 * 64];
  __shared__ bf16_t Bs[64 * 64];
  const int bm = blockIdx.x * 64, bn = blockIdx.y * 64;
  const int t = threadIdx.x;
  const int lane = t & 63, wave = t >> 6;
  const int wm = wave & 1, wn = wave >> 1;
  const int l15 = lane & 15, l4 = lane >> 4;
  f32x4 acc[2][2] = {{{0.f, 0.f, 0.f, 0.f}, {0.f, 0.f, 0.f, 0.f}},
                     {{0.f, 0.f, 0.f, 0.f}, {0.f, 0.f, 0.f, 0.f}}};

  for (int k0 = 0; k0 < 1024; k0 += 64) {
#pragma unroll
    for (int r = 0; r < 2; r++) {
      const int off = (r * 256 + t) * 16;
      const int row = off >> 7;
      const int g = (off >> 4) & 7;
      const int scb = ((g ^ (row & 7)) << 4);
      gload_lds16((const char*)Abf + (size_t)(bm + row) * 2048 + k0 * 2 + scb, (char*)As + off);
      gload_lds16((const char*)Bt + (size_t)(bn + row) * 2048 + k0 * 2 + scb, (char*)Bs + off);
    }
    __syncthreads();
#pragma unroll
    for (int ks = 0; ks < 2; ks++) {
      const int ar0 = wm * 32 + l15, ar1 = ar0 + 16;
      const int br0 = wn * 32 + l15, br1 = br0 + 16;
      const int gA = ks * 4 + l4;
      bf16x8 a0 = *(const bf16x8*)((const char*)As + ar0 * 128 + ((gA ^ (ar0 & 7)) << 4));
      bf16x8 a1 = *(const bf16x8*)((const char*)As + ar1 * 128 + ((gA ^ (ar1 & 7)) << 4));
      bf16x8 b0 = *(const bf16x8*)((const char*)Bs + br0 * 128 + ((gA ^ (br0 & 7)) << 4));
      bf16x8 b1 = *(const bf16x8*)((const char*)Bs + br1 * 128 + ((gA ^ (br1 & 7)) << 4));
      acc[0][0] = __builtin_amdgcn_mfma_f32_16x16x32_bf16(a0, b0, acc[0][0], 0, 0, 0);
      acc[0][1] = __builtin_amdgcn_mfma_f32_16x16x32_bf16(a0, b1, acc[0][1], 0, 0, 0);
      acc[1][0] = __builtin_amdgcn_mfma_f32_16x16x32_bf16(a1, b0, acc[1][0], 0, 0, 0);
      acc[1][1] = __builtin_amdgcn_mfma_f32_16x16x32_bf16(a1, b1, acc[1][1], 0, 0, 0);
    }
    __syncthreads();
  }
#pragma unroll
  for (int mi = 0; mi < 2; mi++)
#pragma unroll
    for (int nj = 0; nj < 2; nj++)
#pragma unroll
      for (int r = 0; r < 4; r++) {
        const int m = bm + wm * 32 + mi * 16 + l4 * 4 + r;
        const int n = bn + wn * 32 + nj * 16 + l15;
        float v = acc[mi][nj][r] + bias[n];
        C[(size_t)m * FFN_ + n] = fmaxf(v, 0.f);
      }
}

__global__ void k_w2t(const float* __restrict__ W2, float* __restrict__ W2t) {
  int idx = blockIdx.x * 256 + threadIdx.x;
  if (idx < OUT_ * FFN_) {
    int n = idx / FFN_, k = idx % FFN_;
    W2t[idx] = W2[(size_t)k * OUT_ + n];
  }
}

__global__ __launch_bounds__(256) void k_ffn2(const float* __restrict__ hid, const float* __restrict__ W2t,
                                              const float* __restrict__ b2, float* __restrict__ out) {
  const int b0 = blockIdx.x * 2;
  const int t = threadIdx.x, wave = t >> 6, lane = t & 63;
  float4 h0[8], h1[8];
  const float* r0 = hid + (size_t)b0 * FFN_;
#pragma unroll
  for (int j = 0; j < 8; j++) {
    h0[j] = *(const float4*)&r0[lane * 4 + j * 256];
    h1[j] = *(const float4*)&r0[FFN_ + lane * 4 + j * 256];
  }
  for (int n = wave; n < OUT_; n += 4) {
    const float* wrow = W2t + (size_t)n * FFN_;
    float s0 = 0.f, s1 = 0.f;
#pragma unroll
    for (int j = 0; j < 8; j++) {
      float4 w4 = *(const float4*)&wrow[lane * 4 + j * 256];
      s0 += w4.x * h0[j].x + w4.y * h0[j].y + w4.z * h0[j].z + w4.w * h0[j].w;
      s1 += w4.x * h1[j].x + w4.y * h1[j].y + w4.z * h1[j].z + w4.w * h1[j].w;
    }
    s0 = wred_sum(s0);
    s1 = wred_sum(s1);
    if (lane == 0) {
      out[(size_t)b0 * OUT_ + n] = s0 + b2[n];
      out[(size_t)(b0 + 1) * OUT_ + n] = s1 + b2[n];
    }
  }
}

extern "C" void kernel_launch(void* const* d_in, const int* in_sizes, int n_in,
                              void* d_out, int out_size, void* d_ws, size_t ws_size,
                              hipStream_t stream) {
  const float* lo = (const float*)d_in[0];
  const float* ro = (const float*)d_in[1];
  const float* la = (const float*)d_in[2];
  const float* ra = (const float*)d_in[3];
  const float* noise = (const float*)d_in[6];
  const float* w_i_w = (const float*)d_in[7];
  const float* prj_w = (const float*)d_in[9];
  const float* prj_b = (const float*)d_in[10];
  const float* W1 = (const float*)d_in[11];
  const float* b1 = (const float*)d_in[12];
  const float* W2 = (const float*)d_in[13];
  const float* b2 = (const float*)d_in[14];

  float* out = (float*)d_out;
  float* o_logits = out;                  // [1024,86]
  float* o_hout  = out + 88064;           // [1024,512]
  float* o_hpert = o_hout + 524288;       // [1024,512]
  float* o_ls    = o_hpert + 524288;      // [65536]
  float* o_rs    = o_ls + 65536;          // [65536]
  float* o_lo    = o_rs + 65536;          // [1024,512]
  float* o_ro    = o_lo + 524288;         // [1024,512]

  float* ws = (float*)d_ws;
  float* T    = ws; ws += 2048 * 512;     // [ro;lo] @ prj_w + prj_b
  float* uLR  = ws; ws += 2048 * 512;     // T @ w_i_w^T
  float* pL   = ws; ws += B_ * H_;
  float* pR   = ws; ws += B_ * H_;
  float* hid  = ws; ws += B_ * FFN_;
  float* W2t  = ws; ws += OUT_ * FFN_;
  bf16_t* pairbf = (bf16_t*)ws; ws += B_ * 1024 / 2;
  bf16_t* W1t    = (bf16_t*)ws; ws += FFN_ * 1024 / 2;

  // T = [ro;lo] @ prj_w + prj_b   (NN, 2048x512x512)
  gemm64<false, true><<<dim3(32, 8), 256, 0, stream>>>(ro, lo, 1024, prj_w, prj_b, T, 512, 512);
  // uLR = T @ w_i_w^T             (NT, 2048x512x512; additive const cancels in softmax)
  gemm64<true, false><<<dim3(32, 8), 256, 0, stream>>>(T, T, 1 << 30, w_i_w, nullptr, uLR, 512, 512);
  k_w1t<<<dim3(64, 32), 256, 0, stream>>>(W1, W1t);
  k_atoms10<<<2048, 256, 0, stream>>>(la, ra, uLR, o_ls, o_rs, pL, pR);
  k_pert<<<1024, 512, 0, stream>>>(lo, ro, noise, pL, pR, o_hout, o_hpert, pairbf);
  k_ffn1<<<dim3(16, 32), 256, 0, stream>>>(pairbf, W1t, b1, hid);
  k_w2t<<<688, 256, 0, stream>>>(W2, W2t);
  k_ffn2<<<512, 256, 0, stream>>>(hid, W2t, b2, o_logits);
  hipMemcpyAsync(o_lo, lo, (size_t)B_ * H_ * 4, hipMemcpyDeviceToDevice, stream);
  hipMemcpyAsync(o_ro, ro, (size_t)B_ * H_ * 4, hipMemcpyDeviceToDevice, stream);
}

// Round 18
// 161.390 us; speedup vs baseline: 1.2803x; 1.2803x over previous
//
#include <hip/hip_runtime.h>
#include <hip/hip_bf16.h>
#include <float.h>

#define B_ 1024
#define H_ 512
#define N_ (B_ * 64)
#define FFN_ 2048
#define OUT_ 86

typedef __bf16 bf16_t;
typedef __attribute__((ext_vector_type(8))) __bf16 bf16x8;
typedef __attribute__((ext_vector_type(4))) float f32x4;

__device__ __forceinline__ float wred_sum(float v) {
#pragma unroll
  for (int m = 32; m; m >>= 1) v += __shfl_xor(v, m);
  return v;
}
__device__ __forceinline__ float wred_max(float v) {
#pragma unroll
  for (int m = 32; m; m >>= 1) v = fmaxf(v, __shfl_xor(v, m));
  return v;
}

__device__ __forceinline__ void gload_lds16(const void* g, void* l) {
  __builtin_amdgcn_global_load_lds((const __attribute__((address_space(1))) unsigned int*)g,
                                   (__attribute__((address_space(3))) unsigned int*)l, 16, 0, 0);
}

// f32 tiled GEMM, 64x64 tile, BK=16, 4x4 accum. A split across two row blocks.
template <bool BT, bool BIAS>
__global__ __launch_bounds__(256) void gemm64(const float* __restrict__ A1, const float* __restrict__ A2,
                                              int M1, const float* __restrict__ Bm,
                                              const float* __restrict__ bias, float* __restrict__ C,
                                              int N, int K) {
  __shared__ float As[16][68];
  __shared__ float Bs[16][68];
  const int bm = blockIdx.x * 64, bn = blockIdx.y * 64;
  const float* __restrict__ A = (bm < M1) ? (A1 + (size_t)bm * K) : (A2 + (size_t)(bm - M1) * K);
  const int t = threadIdx.x;
  const int tx = t & 15, ty = t >> 4;
  float acc[4][4] = {};
  for (int k0 = 0; k0 < K; k0 += 16) {
#pragma unroll
    for (int i = 0; i < 4; i++) {
      int m = (t >> 4) + i * 16;
      As[t & 15][m] = A[(size_t)m * K + k0 + (t & 15)];
    }
    if (BT) {
#pragma unroll
      for (int i = 0; i < 4; i++) {
        int n = (t >> 4) + i * 16;
        Bs[t & 15][n] = Bm[(size_t)(bn + n) * K + k0 + (t & 15)];
      }
    } else {
#pragma unroll
      for (int i = 0; i < 4; i++) {
        int kk = (t >> 6) + i * 4;
        Bs[kk][t & 63] = Bm[(size_t)(k0 + kk) * N + bn + (t & 63)];
      }
    }
    __syncthreads();
#pragma unroll
    for (int kk = 0; kk < 16; kk++) {
      float4 av = *(const float4*)&As[kk][ty * 4];
      float4 bv = *(const float4*)&Bs[kk][tx * 4];
      float a_[4] = {av.x, av.y, av.z, av.w};
      float b_[4] = {bv.x, bv.y, bv.z, bv.w};
#pragma unroll
      for (int i = 0; i < 4; i++)
#pragma unroll
        for (int j = 0; j < 4; j++) acc[i][j] += a_[i] * b_[j];
    }
    __syncthreads();
  }
#pragma unroll
  for (int i = 0; i < 4; i++) {
    int m = bm + ty * 4 + i;
    float tmp[4];
#pragma unroll
    for (int j = 0; j < 4; j++) {
      float x = acc[i][j];
      if (BIAS) x += bias[bn + tx * 4 + j];
      tmp[j] = x;
    }
    float4 v;
    v.x = tmp[0]; v.y = tmp[1]; v.z = tmp[2]; v.w = tmp[3];
    *(float4*)&C[(size_t)m * N + bn + tx * 4] = v;
  }
}

// Fused scores+softmax+pool, SINGLE PASS, asm-pinned tile + STAGGERED consume.
// r16 (burst: one vmcnt(0) after 32 loads) = 1.5 TB/s; r17 (ring, counted
// waits, continuous issue) = 2.65 TB/s but 2x traffic. This keeps the tile
// (single 133MB pass) and consumes row i after vmcnt(30-2i): FMA work overlaps
// the still-streaming load tail. sched_barrier(0) per wait (rule #18).
__global__ __launch_bounds__(256, 2) void k_atoms9(const float* __restrict__ atomL, const float* __restrict__ atomR,
                                                   const float* __restrict__ uLR,
                                                   float* __restrict__ scoresL, float* __restrict__ scoresR,
                                                   float* __restrict__ pL, float* __restrict__ pR) {
  const int pair = blockIdx.x;                 // 0..2047
  const int side = pair >> 10, b = pair & 1023;
  const int t = threadIdx.x, wave = t >> 6, lane = t & 63;

  __shared__ float s_all[64];
  __shared__ float s_nrm[64];
  __shared__ float pp[4][512];

  const float* __restrict__ atom = side ? atomR : atomL;
  const float* __restrict__ u = uLR + (size_t)pair * H_;
  f32x4 u0 = *(const f32x4*)&u[lane * 4];
  f32x4 u1 = *(const f32x4*)&u[256 + lane * 4];

  const float* __restrict__ base = atom + ((size_t)b * 64 + wave * 16) * H_ + lane * 4;

  // ---- issue ALL 32 tile loads (asm-pinned, tile retained for the pool) ----
  f32x4 A0[16], A1[16];
#pragma unroll
  for (int i = 0; i < 16; i++) {
    const float* r0 = base + (size_t)i * H_;
    asm volatile("global_load_dwordx4 %0, %1, off" : "=&v"(A0[i]) : "v"(r0) : "memory");
    asm volatile("global_load_dwordx4 %0, %1, off" : "=&v"(A1[i]) : "v"(r0 + 256) : "memory");
  }

  // ---- staggered consume: row i ready when outstanding <= 30-2i ----
  float d[16];
#pragma unroll
  for (int i = 0; i < 16; i++) {
    switch (30 - 2 * i) {
      case 30: asm volatile("s_waitcnt vmcnt(30)" ::: "memory"); break;
      case 28: asm volatile("s_waitcnt vmcnt(28)" ::: "memory"); break;
      case 26: asm volatile("s_waitcnt vmcnt(26)" ::: "memory"); break;
      case 24: asm volatile("s_waitcnt vmcnt(24)" ::: "memory"); break;
      case 22: asm volatile("s_waitcnt vmcnt(22)" ::: "memory"); break;
      case 20: asm volatile("s_waitcnt vmcnt(20)" ::: "memory"); break;
      case 18: asm volatile("s_waitcnt vmcnt(18)" ::: "memory"); break;
      case 16: asm volatile("s_waitcnt vmcnt(16)" ::: "memory"); break;
      case 14: asm volatile("s_waitcnt vmcnt(14)" ::: "memory"); break;
      case 12: asm volatile("s_waitcnt vmcnt(12)" ::: "memory"); break;
      case 10: asm volatile("s_waitcnt vmcnt(10)" ::: "memory"); break;
      case 8:  asm volatile("s_waitcnt vmcnt(8)"  ::: "memory"); break;
      case 6:  asm volatile("s_waitcnt vmcnt(6)"  ::: "memory"); break;
      case 4:  asm volatile("s_waitcnt vmcnt(4)"  ::: "memory"); break;
      case 2:  asm volatile("s_waitcnt vmcnt(2)"  ::: "memory"); break;
      default: asm volatile("s_waitcnt vmcnt(0)"  ::: "memory"); break;
    }
    __builtin_amdgcn_sched_barrier(0);  // rule #18: consumer stays after its wait
    d[i] = A0[i].x * u0.x + A0[i].y * u0.y + A0[i].z * u0.z + A0[i].w * u0.w +
           A1[i].x * u1.x + A1[i].y * u1.y + A1[i].z * u1.z + A1[i].w * u1.w;
  }

  // ---- batch reduction + block softmax ----
#pragma unroll
  for (int i = 0; i < 16; i++) d[i] = wred_sum(d[i]);
  if (lane < 16) {
    float myv = 0.f;
#pragma unroll
    for (int i = 0; i < 16; i++) myv = (lane == i) ? d[i] : myv;  // static idx
    s_all[wave * 16 + lane] = myv;
  }
  __syncthreads();
  {
    float sv = s_all[lane];
    float M = wred_max(sv);
    float e = __expf(sv - M);
    float Z = wred_sum(e);
    float w_n = e / Z;
    if (wave == 0) {
      s_nrm[lane] = w_n;
      (side ? scoresR : scoresL)[(size_t)b * 64 + lane] = w_n;
    }
  }
  __syncthreads();

  // ---- pool from pinned regs (atoms touched exactly once) ----
  f32x4 q0 = {0.f, 0.f, 0.f, 0.f}, q1 = {0.f, 0.f, 0.f, 0.f};
#pragma unroll
  for (int i = 0; i < 16; i++) {
    const float w = s_nrm[wave * 16 + i];
    q0.x += w * A0[i].x; q0.y += w * A0[i].y; q0.z += w * A0[i].z; q0.w += w * A0[i].w;
    q1.x += w * A1[i].x; q1.y += w * A1[i].y; q1.z += w * A1[i].z; q1.w += w * A1[i].w;
  }
  *(f32x4*)&pp[wave][lane * 4] = q0;
  *(f32x4*)&pp[wave][256 + lane * 4] = q1;
  __syncthreads();

  float v0 = pp[0][t] + pp[1][t] + pp[2][t] + pp[3][t];
  float v1 = pp[0][t + 256] + pp[1][t + 256] + pp[2][t + 256] + pp[3][t + 256];
  float* p = (side ? pR : pL) + (size_t)b * H_;
  p[t] = v0;
  p[t + 256] = v1;
}

// perturbation + bf16 pair assembly
__global__ __launch_bounds__(512) void k_pert(const float* __restrict__ lo, const float* __restrict__ ro,
                                              const float* __restrict__ noise,
                                              const float* __restrict__ pL, const float* __restrict__ pR,
                                              float* __restrict__ h_out, float* __restrict__ h_pert,
                                              bf16_t* __restrict__ pairbf) {
  const int b = blockIdx.x, t = threadIdx.x;
  float nv = noise[(size_t)b * H_ + t];
  float sq = nv * nv;
  sq = wred_sum(sq);
  __shared__ float red[8];
  if ((t & 63) == 0) red[t >> 6] = sq;
  __syncthreads();
  float tot = 0.f;
#pragma unroll
  for (int i = 0; i < 8; i++) tot += red[i];
  float nrm = fmaxf(sqrtf(tot), 1e-12f);
  float nn = nv / nrm * 0.1f;
  float h = ro[(size_t)b * H_ + t] * pL[(size_t)b * H_ + t];
  float tt = lo[(size_t)b * H_ + t] * pR[(size_t)b * H_ + t];
  float sh = (h > 0.f) ? 1.f : ((h < 0.f) ? -1.f : 0.f);
  float st = (tt > 0.f) ? 1.f : ((tt < 0.f) ? -1.f : 0.f);
  float hp = h + sh * nn;
  float tp = tt + st * nn;
  h_out[(size_t)b * H_ + t] = h;
  h_pert[(size_t)b * H_ + t] = hp;
  pairbf[(size_t)b * 1024 + t] = (bf16_t)hp;
  pairbf[(size_t)b * 1024 + 512 + t] = (bf16_t)tp;
}

// W1 [1024][2048] f32 -> W1t [2048][1024] bf16 (transpose + cast, LDS tiled)
__global__ __launch_bounds__(256) void k_w1t(const float* __restrict__ W1, bf16_t* __restrict__ W1t) {
  __shared__ float tile[32][33];
  const int bx = blockIdx.x;
  const int by = blockIdx.y;
  const int tx = threadIdx.x & 31, ty = threadIdx.x >> 5;
#pragma unroll
  for (int i = ty; i < 32; i += 8)
    tile[i][tx] = W1[(size_t)(by * 32 + i) * FFN_ + bx * 32 + tx];
  __syncthreads();
#pragma unroll
  for (int i = ty; i < 32; i += 8)
    W1t[(size_t)(bx * 32 + i) * 1024 + by * 32 + tx] = (bf16_t)tile[tx][i];
}

// FFN1 via MFMA bf16 (64x64 tile, XOR-swizzled source + matching swizzled read)
__global__ __launch_bounds__(256) void k_ffn1(const bf16_t* __restrict__ Abf, const bf16_t* __restrict__ Bt,
                                              const float* __restrict__ bias, float* __restrict__ C) {
  __shared__ bf16_t As[64 * 64];
  __shared__ bf16_t Bs[64 * 64];
  const int bm = blockIdx.x * 64, bn = blockIdx.y * 64;
  const int t = threadIdx.x;
  const int lane = t & 63, wave = t >> 6;
  const int wm = wave & 1, wn = wave >> 1;
  const int l15 = lane & 15, l4 = lane >> 4;
  f32x4 acc[2][2] = {{{0.f, 0.f, 0.f, 0.f}, {0.f, 0.f, 0.f, 0.f}},
                     {{0.f, 0.f, 0.f, 0.f}, {0.f, 0.f, 0.f, 0.f}}};

  for (int k0 = 0; k0 < 1024; k0 += 64) {
#pragma unroll
    for (int r = 0; r < 2; r++) {
      const int off = (r * 256 + t) * 16;
      const int row = off >> 7;
      const int g = (off >> 4) & 7;
      const int scb = ((g ^ (row & 7)) << 4);
      gload_lds16((const char*)Abf + (size_t)(bm + row) * 2048 + k0 * 2 + scb, (char*)As + off);
      gload_lds16((const char*)Bt + (size_t)(bn + row) * 2048 + k0 * 2 + scb, (char*)Bs + off);
    }
    __syncthreads();
#pragma unroll
    for (int ks = 0; ks < 2; ks++) {
      const int ar0 = wm * 32 + l15, ar1 = ar0 + 16;
      const int br0 = wn * 32 + l15, br1 = br0 + 16;
      const int gA = ks * 4 + l4;
      bf16x8 a0 = *(const bf16x8*)((const char*)As + ar0 * 128 + ((gA ^ (ar0 & 7)) << 4));
      bf16x8 a1 = *(const bf16x8*)((const char*)As + ar1 * 128 + ((gA ^ (ar1 & 7)) << 4));
      bf16x8 b0 = *(const bf16x8*)((const char*)Bs + br0 * 128 + ((gA ^ (br0 & 7)) << 4));
      bf16x8 b1 = *(const bf16x8*)((const char*)Bs + br1 * 128 + ((gA ^ (br1 & 7)) << 4));
      acc[0][0] = __builtin_amdgcn_mfma_f32_16x16x32_bf16(a0, b0, acc[0][0], 0, 0, 0);
      acc[0][1] = __builtin_amdgcn_mfma_f32_16x16x32_bf16(a0, b1, acc[0][1], 0, 0, 0);
      acc[1][0] = __builtin_amdgcn_mfma_f32_16x16x32_bf16(a1, b0, acc[1][0], 0, 0, 0);
      acc[1][1] = __builtin_amdgcn_mfma_f32_16x16x32_bf16(a1, b1, acc[1][1], 0, 0, 0);
    }
    __syncthreads();
  }
#pragma unroll
  for (int mi = 0; mi < 2; mi++)
#pragma unroll
    for (int nj = 0; nj < 2; nj++)
#pragma unroll
      for (int r = 0; r < 4; r++) {
        const int m = bm + wm * 32 + mi * 16 + l4 * 4 + r;
        const int n = bn + wn * 32 + nj * 16 + l15;
        float v = acc[mi][nj][r] + bias[n];
        C[(size_t)m * FFN_ + n] = fmaxf(v, 0.f);
      }
}

__global__ void k_w2t(const float* __restrict__ W2, float* __restrict__ W2t) {
  int idx = blockIdx.x * 256 + threadIdx.x;
  if (idx < OUT_ * FFN_) {
    int n = idx / FFN_, k = idx % FFN_;
    W2t[idx] = W2[(size_t)k * OUT_ + n];
  }
}

__global__ __launch_bounds__(256) void k_ffn2(const float* __restrict__ hid, const float* __restrict__ W2t,
                                              const float* __restrict__ b2, float* __restrict__ out) {
  const int b0 = blockIdx.x * 2;
  const int t = threadIdx.x, wave = t >> 6, lane = t & 63;
  float4 h0[8], h1[8];
  const float* r0 = hid + (size_t)b0 * FFN_;
#pragma unroll
  for (int j = 0; j < 8; j++) {
    h0[j] = *(const float4*)&r0[lane * 4 + j * 256];
    h1[j] = *(const float4*)&r0[FFN_ + lane * 4 + j * 256];
  }
  for (int n = wave; n < OUT_; n += 4) {
    const float* wrow = W2t + (size_t)n * FFN_;
    float s0 = 0.f, s1 = 0.f;
#pragma unroll
    for (int j = 0; j < 8; j++) {
      float4 w4 = *(const float4*)&wrow[lane * 4 + j * 256];
      s0 += w4.x * h0[j].x + w4.y * h0[j].y + w4.z * h0[j].z + w4.w * h0[j].w;
      s1 += w4.x * h1[j].x + w4.y * h1[j].y + w4.z * h1[j].z + w4.w * h1[j].w;
    }
    s0 = wred_sum(s0);
    s1 = wred_sum(s1);
    if (lane == 0) {
      out[(size_t)b0 * OUT_ + n] = s0 + b2[n];
      out[(size_t)(b0 + 1) * OUT_ + n] = s1 + b2[n];
    }
  }
}

extern "C" void kernel_launch(void* const* d_in, const int* in_sizes, int n_in,
                              void* d_out, int out_size, void* d_ws, size_t ws_size,
                              hipStream_t stream) {
  const float* lo = (const float*)d_in[0];
  const float* ro = (const float*)d_in[1];
  const float* la = (const float*)d_in[2];
  const float* ra = (const float*)d_in[3];
  const float* noise = (const float*)d_in[6];
  const float* w_i_w = (const float*)d_in[7];
  const float* prj_w = (const float*)d_in[9];
  const float* prj_b = (const float*)d_in[10];
  const float* W1 = (const float*)d_in[11];
  const float* b1 = (const float*)d_in[12];
  const float* W2 = (const float*)d_in[13];
  const float* b2 = (const float*)d_in[14];

  float* out = (float*)d_out;
  float* o_logits = out;                  // [1024,86]
  float* o_hout  = out + 88064;           // [1024,512]
  float* o_hpert = o_hout + 524288;       // [1024,512]
  float* o_ls    = o_hpert + 524288;      // [65536]
  float* o_rs    = o_ls + 65536;          // [65536]
  float* o_lo    = o_rs + 65536;          // [1024,512]
  float* o_ro    = o_lo + 524288;         // [1024,512]

  float* ws = (float*)d_ws;
  float* T    = ws; ws += 2048 * 512;     // [ro;lo] @ prj_w + prj_b
  float* uLR  = ws; ws += 2048 * 512;     // T @ w_i_w^T
  float* pL   = ws; ws += B_ * H_;
  float* pR   = ws; ws += B_ * H_;
  float* hid  = ws; ws += B_ * FFN_;
  float* W2t  = ws; ws += OUT_ * FFN_;
  bf16_t* pairbf = (bf16_t*)ws; ws += B_ * 1024 / 2;
  bf16_t* W1t    = (bf16_t*)ws; ws += FFN_ * 1024 / 2;

  // T = [ro;lo] @ prj_w + prj_b   (NN, 2048x512x512)
  gemm64<false, true><<<dim3(32, 8), 256, 0, stream>>>(ro, lo, 1024, prj_w, prj_b, T, 512, 512);
  // uLR = T @ w_i_w^T             (NT, 2048x512x512; additive const cancels in softmax)
  gemm64<true, false><<<dim3(32, 8), 256, 0, stream>>>(T, T, 1 << 30, w_i_w, nullptr, uLR, 512, 512);
  k_w1t<<<dim3(64, 32), 256, 0, stream>>>(W1, W1t);
  k_atoms9<<<2048, 256, 0, stream>>>(la, ra, uLR, o_ls, o_rs, pL, pR);
  k_pert<<<1024, 512, 0, stream>>>(lo, ro, noise, pL, pR, o_hout, o_hpert, pairbf);
  k_ffn1<<<dim3(16, 32), 256, 0, stream>>>(pairbf, W1t, b1, hid);
  k_w2t<<<688, 256, 0, stream>>>(W2, W2t);
  k_ffn2<<<512, 256, 0, stream>>>(hid, W2t, b2, o_logits);
  hipMemcpyAsync(o_lo, lo, (size_t)B_ * H_ * 4, hipMemcpyDeviceToDevice, stream);
  hipMemcpyAsync(o_ro, ro, (size_t)B_ * H_ * 4, hipMemcpyDeviceToDevice, stream);
}